// Round 1
// baseline (202.899 us; speedup 1.0000x reference)
//
#include <hip/hip_runtime.h>

// VQ-VAE VectorQuantizer for MI355X — register-resident x, wave-uniform e-stream.
// inputs: d_in[0] = inputs [64, 64, 32, 32] fp32 (NCHW), d_in[1] = emb_w [512, 64] fp32
// output d_out (fp32): [loss(1), quantized NCHW (64*64*32*32), idx (65536)]
//
// Correctness note: the reference computes dist = ||x||^2 + ||e||^2 - 2 x.e in fp32,
// where ||x||^2 ~ 64 quantizes dist to a ~7.6e-6 grid; ~100/65536 points have quantized
// TIES that argmin resolves by first index. We bit-replicate that arithmetic
// (numpy pairwise-sum order for the norms, fp32 rounding sequence for dist: sequential
// fmaf over d=0..63, then fp32((sx+nk) - 2*dot)) and tie-break by smallest index.
//
// Structure (v2): the previous version was LDS-pipe-bound (2.1 GB of ds_read traffic,
// 4.3M bank-conflict cycles). Now each thread holds x for 2 points in 128 VGPRs; the
// 4 waves of a block split the 512 codes 4-way so the e operand is wave-uniform and
// streams via broadcast global_load_dwordx4 from L1/L2 (emb = 128 KB, identical stream
// for every wave). Inner loop has ZERO LDS traffic. ||e||^2 is fused into the block
// prologue (kills the serialized grid=2 norm kernel + one launch).

#define D_    64
#define HW_   1024
#define N_    65536
#define K_    512
#define M_    128    // points per block
#define NDTOT (N_ * D_)

__global__ __launch_bounds__(256, 2) void vq_fused_kernel(const float* __restrict__ inp,
                                                          const float* __restrict__ emb,
                                                          float* __restrict__ out) {
    __shared__ float ldsx[D_ * M_];   // xT[d][p], 32 KB (dot prologue + epilogue)
    __shared__ float ldsn[K_];        // ||e_k||^2
    __shared__ float sv[4 * M_];      // per-wave argmin value
    __shared__ int   si[4 * M_];      // per-wave argmin index
    __shared__ int   fi[M_];          // final index per point
    __shared__ float partial[4];      // loss partials

    const int tid  = threadIdx.x;
    const int lane = tid & 63;
    const int w    = tid >> 6;            // wave id 0..3 -> code range
    const int n0   = blockIdx.x * M_;
    const int b    = n0 >> 10;
    const int hw0  = n0 & 1023;
    const float* xbase = inp + b * (D_ * HW_) + hw0;

    // ---- stage xT[d][p] (coalesced: 128 consecutive floats per d) ----
#pragma unroll
    for (int i = 0; i < 8; ++i) {
        int q  = i * 256 + tid;           // 0..2047 = 64 d * 32 quads
        int d  = q >> 5;
        int pq = q & 31;
        float4 v = *(const float4*)(xbase + d * HW_ + pq * 4);
        *(float4*)(ldsx + d * M_ + pq * 4) = v;
    }

    // ---- fused ||e_k||^2, numpy pairwise order (2 codes/thread) ----
    // Overlaps the x-staging load latency; emb gather is L2-served (128 KB, hot after
    // the first resident blocks touch it).
#pragma unroll
    for (int c = 0; c < 2; ++c) {
        const int k = c * 256 + tid;
        const float* e = emb + k * D_;
        float el[64];
#pragma unroll
        for (int q = 0; q < 16; ++q) {
            float4 v = *(const float4*)(e + q * 4);
            el[4 * q + 0] = v.x; el[4 * q + 1] = v.y;
            el[4 * q + 2] = v.z; el[4 * q + 3] = v.w;
        }
        float r[8];
#pragma unroll
        for (int j = 0; j < 8; ++j) r[j] = __fmul_rn(el[j], el[j]);
#pragma unroll
        for (int i = 1; i < 8; ++i)
#pragma unroll
            for (int j = 0; j < 8; ++j)
                r[j] = __fadd_rn(r[j], __fmul_rn(el[i * 8 + j], el[i * 8 + j]));
        ldsn[k] = __fadd_rn(__fadd_rn(__fadd_rn(r[0], r[1]), __fadd_rn(r[2], r[3])),
                            __fadd_rn(__fadd_rn(r[4], r[5]), __fadd_rn(r[6], r[7])));
    }
    __syncthreads();

    // ---- x for points 2*lane, 2*lane+1 into registers (128 VGPR) ----
    float x0[64], x1[64];
#pragma unroll
    for (int d = 0; d < 64; ++d) {
        float2 v = *(const float2*)(ldsx + d * M_ + 2 * lane);   // 2-way bank alias: free
        x0[d] = v.x; x1[d] = v.y;
    }

    // ---- ||x||^2, numpy pairwise order ----
    float r0[8], r1[8];
#pragma unroll
    for (int j = 0; j < 8; ++j) {
        r0[j] = __fmul_rn(x0[j], x0[j]);
        r1[j] = __fmul_rn(x1[j], x1[j]);
    }
#pragma unroll
    for (int i = 1; i < 8; ++i)
#pragma unroll
        for (int j = 0; j < 8; ++j) {
            r0[j] = __fadd_rn(r0[j], __fmul_rn(x0[i * 8 + j], x0[i * 8 + j]));
            r1[j] = __fadd_rn(r1[j], __fmul_rn(x1[i * 8 + j], x1[i * 8 + j]));
        }
    const float sx0 = __fadd_rn(__fadd_rn(__fadd_rn(r0[0], r0[1]), __fadd_rn(r0[2], r0[3])),
                                __fadd_rn(__fadd_rn(r0[4], r0[5]), __fadd_rn(r0[6], r0[7])));
    const float sx1 = __fadd_rn(__fadd_rn(__fadd_rn(r1[0], r1[1]), __fadd_rn(r1[2], r1[3])),
                                __fadd_rn(__fadd_rn(r1[4], r1[5]), __fadd_rn(r1[6], r1[7])));

    // ---- wave w scans codes [w*128, w*128+128), e via wave-uniform broadcast loads ----
    float runv0 = 3.4e38f, runv1 = 3.4e38f;
    int   runi0 = 0,       runi1 = 0;
    const int k0 = w << 7;
    const float* ew = emb + k0 * D_;
#pragma unroll 2
    for (int kk = 0; kk < 128; ++kk) {
        const float* ek = ew + kk * D_;
        const float nk = ldsn[k0 + kk];       // uniform ds_read_b32, broadcast
        float acc0 = 0.f, acc1 = 0.f;
#pragma unroll
        for (int q = 0; q < 16; ++q) {
            float4 ev = *(const float4*)(ek + q * 4);   // uniform addr -> 16B broadcast
            acc0 = fmaf(x0[4 * q + 0], ev.x, acc0); acc1 = fmaf(x1[4 * q + 0], ev.x, acc1);
            acc0 = fmaf(x0[4 * q + 1], ev.y, acc0); acc1 = fmaf(x1[4 * q + 1], ev.y, acc1);
            acc0 = fmaf(x0[4 * q + 2], ev.z, acc0); acc1 = fmaf(x1[4 * q + 2], ev.z, acc1);
            acc0 = fmaf(x0[4 * q + 3], ev.w, acc0); acc1 = fmaf(x1[4 * q + 3], ev.w, acc1);
        }
        // dist = fp32(fp32(sx + n_k) - 2*dot); -2*acc exact (power-of-two scale),
        // so fadd vs contracted fma are bit-identical. Strict < keeps first index.
        float t0 = __fadd_rn(sx0, nk);
        float v0 = __fadd_rn(t0, -2.0f * acc0);
        if (v0 < runv0) { runv0 = v0; runi0 = k0 + kk; }
        float t1 = __fadd_rn(sx1, nk);
        float v1 = __fadd_rn(t1, -2.0f * acc1);
        if (v1 < runv1) { runv1 = v1; runi1 = k0 + kk; }
    }

    // ---- cross-wave argmin merge (waves are ascending code blocks) ----
    {
        const int p0 = 2 * lane, p1 = 2 * lane + 1;
        sv[w * M_ + p0] = runv0; si[w * M_ + p0] = runi0;
        sv[w * M_ + p1] = runv1; si[w * M_ + p1] = runi1;
    }
    __syncthreads();
    if (tid < M_) {
        float bv = 3.4e38f; int bi = 0x7fffffff;
#pragma unroll
        for (int g = 0; g < 4; ++g) {
            float v  = sv[g * M_ + tid];
            int   ii = si[g * M_ + tid];
            if (v < bv || (v == bv && ii < bi)) { bv = v; bi = ii; }
        }
        fi[tid] = bi;
        out[1 + NDTOT + n0 + tid] = (float)bi;   // idx as float
    }
    __syncthreads();

    // ---- quantized output (NCHW) + loss partial ----
    float* obase = out + 1 + b * (D_ * HW_) + hw0;
    float local = 0.f;
    for (int i = 0; i < 32; ++i) {
        int q = i * 256 + tid;              // 0..8191 = 64 d * 128 p
        int d = q >> 7;
        int p = q & 127;
        int idx = fi[p];
        float e  = emb[idx * D_ + d];       // gather, L1-hot
        float xv = ldsx[d * M_ + p];
        float df = e - xv;
        local = fmaf(df, df, local);
        obase[d * HW_ + p] = e;             // coalesced per d-row
    }
#pragma unroll
    for (int off = 32; off > 0; off >>= 1)
        local += __shfl_down(local, off, 64);
    if ((tid & 63) == 0) partial[tid >> 6] = local;
    __syncthreads();
    if (tid == 0) {
        float t = partial[0] + partial[1] + partial[2] + partial[3];
        atomicAdd(out, t * (1.25f / (float)NDTOT));   // loss = 1.25 * mean((q-x)^2)
    }
}

extern "C" void kernel_launch(void* const* d_in, const int* in_sizes, int n_in,
                              void* d_out, int out_size, void* d_ws, size_t ws_size,
                              hipStream_t stream) {
    const float* inp = (const float*)d_in[0];
    const float* emb = (const float*)d_in[1];
    float* out = (float*)d_out;
    (void)d_ws; (void)ws_size;

    hipMemsetAsync(d_out, 0, sizeof(float), stream);   // loss accumulator
    vq_fused_kernel<<<512, 256, 0, stream>>>(inp, emb, out);
}

// Round 2
// 154.078 us; speedup vs baseline: 1.3169x; 1.3169x over previous
//
#include <hip/hip_runtime.h>

// VQ-VAE VectorQuantizer for MI355X — register-resident x, LDS-chunked wave-uniform e.
// inputs: d_in[0] = inputs [64, 64, 32, 32] fp32 (NCHW), d_in[1] = emb_w [512, 64] fp32
// output d_out (fp32): [loss(1), quantized NCHW (64*64*32*32), idx (65536)]
//
// Correctness note: the reference computes dist = ||x||^2 + ||e||^2 - 2 x.e in fp32,
// where ||x||^2 ~ 64 quantizes dist to a ~7.6e-6 grid; ~100/65536 points have quantized
// TIES that argmin resolves by first index. We bit-replicate that arithmetic
// (numpy pairwise-sum order for the norms, fp32 rounding sequence for dist: sequential
// fmaf over d=0..63, then fp32((sx+nk) - 2*dot)) and tie-break by smallest index.
//
// v3 structure: v2 (x in VGPRs, wave-uniform broadcast e) was VMEM-latency-bound
// (16 global_load_dwordx4 per code, ~1100 cy exposed per code at 2 waves/SIMD,
// VALUBusy 28%). Now e streams from LDS: 4 chunks x 128 codes (32 KB), staged
// cooperatively; each wave scans a 32-code slice per chunk via uniform ds_read_b128
// (broadcast, conflict-free). The e-chunks overwrite the x-staging buffer, which
// forces x0/x1 to stay register-resident (v2's compiler re-sank the x loads into
// the loop: VGPR_Count=92 < 128). Inner loop: 128 fmaf + 17 uniform LDS reads ->
// VALU-pipe-bound, floor ~27 us.

#define D_     64
#define HW_    1024
#define N_     65536
#define K_     512
#define M_     128    // points per block
#define CH_    128    // codes per staged LDS chunk
#define NCH_   4
#define WCODES 32     // codes per wave per chunk (4 waves split the chunk)
#define NDTOT  (N_ * D_)

__global__ __launch_bounds__(256, 2) void vq_fused_kernel(const float* __restrict__ inp,
                                                          const float* __restrict__ emb,
                                                          float* __restrict__ out) {
    __shared__ float ebuf[CH_ * D_];   // 32 KB: xT staging first, then e chunks
    __shared__ float ldsn[K_];         // ||e_k||^2
    __shared__ float sv[4 * M_];       // per-wave argmin value
    __shared__ int   si[4 * M_];       // per-wave argmin index
    __shared__ int   fi[M_];           // final index per point

    const int tid  = threadIdx.x;
    const int lane = tid & 63;
    const int w    = tid >> 6;            // wave id 0..3
    const int n0   = blockIdx.x * M_;
    const int b    = n0 >> 10;
    const int hw0  = n0 & 1023;
    const float* xbase = inp + b * (D_ * HW_) + hw0;

    // ---- stage xT[d][p] into ebuf (coalesced: 128 consecutive floats per d) ----
#pragma unroll
    for (int i = 0; i < 8; ++i) {
        int q  = i * 256 + tid;           // 0..2047 = 64 d * 32 quads
        int d  = q >> 5;
        int pq = q & 31;
        float4 v = *(const float4*)(xbase + d * HW_ + pq * 4);
        *(float4*)(ebuf + d * M_ + pq * 4) = v;
    }

    // ---- fused ||e_k||^2, numpy pairwise order (2 codes/thread) ----
    // Overlaps the x-staging latency; emb is 128 KB, L2-hot after first touch.
#pragma unroll
    for (int c = 0; c < 2; ++c) {
        const int k = c * 256 + tid;
        const float* e = emb + k * D_;
        float el[64];
#pragma unroll
        for (int q = 0; q < 16; ++q) {
            float4 v = *(const float4*)(e + q * 4);
            el[4 * q + 0] = v.x; el[4 * q + 1] = v.y;
            el[4 * q + 2] = v.z; el[4 * q + 3] = v.w;
        }
        float r[8];
#pragma unroll
        for (int j = 0; j < 8; ++j) r[j] = __fmul_rn(el[j], el[j]);
#pragma unroll
        for (int i = 1; i < 8; ++i)
#pragma unroll
            for (int j = 0; j < 8; ++j)
                r[j] = __fadd_rn(r[j], __fmul_rn(el[i * 8 + j], el[i * 8 + j]));
        ldsn[k] = __fadd_rn(__fadd_rn(__fadd_rn(r[0], r[1]), __fadd_rn(r[2], r[3])),
                            __fadd_rn(__fadd_rn(r[4], r[5]), __fadd_rn(r[6], r[7])));
    }
    __syncthreads();

    // ---- x for points 2*lane, 2*lane+1 into registers (128 VGPR) ----
    float x0[64], x1[64];
#pragma unroll
    for (int d = 0; d < 64; ++d) {
        float2 v = *(const float2*)(ebuf + d * M_ + 2 * lane);   // 2-way alias: free
        x0[d] = v.x; x1[d] = v.y;
    }

    // ---- ||x||^2, numpy pairwise order ----
    float r0[8], r1[8];
#pragma unroll
    for (int j = 0; j < 8; ++j) {
        r0[j] = __fmul_rn(x0[j], x0[j]);
        r1[j] = __fmul_rn(x1[j], x1[j]);
    }
#pragma unroll
    for (int i = 1; i < 8; ++i)
#pragma unroll
        for (int j = 0; j < 8; ++j) {
            r0[j] = __fadd_rn(r0[j], __fmul_rn(x0[i * 8 + j], x0[i * 8 + j]));
            r1[j] = __fadd_rn(r1[j], __fmul_rn(x1[i * 8 + j], x1[i * 8 + j]));
        }
    const float sx0 = __fadd_rn(__fadd_rn(__fadd_rn(r0[0], r0[1]), __fadd_rn(r0[2], r0[3])),
                                __fadd_rn(__fadd_rn(r0[4], r0[5]), __fadd_rn(r0[6], r0[7])));
    const float sx1 = __fadd_rn(__fadd_rn(__fadd_rn(r1[0], r1[1]), __fadd_rn(r1[2], r1[3])),
                                __fadd_rn(__fadd_rn(r1[4], r1[5]), __fadd_rn(r1[6], r1[7])));

    // ---- main loop: 4 chunks of 128 codes in LDS; wave w scans its 32-code slice ----
    float runv0 = 3.4e38f, runv1 = 3.4e38f;
    int   runi0 = 0,       runi1 = 0;

    for (int c = 0; c < NCH_; ++c) {
        __syncthreads();                  // ebuf free (x reads / prev chunk done)
        // stage chunk c: 32 KB contiguous copy, 8 float4 per thread, coalesced
        const float4* src = (const float4*)(emb + c * (CH_ * D_));
        float4* dst = (float4*)ebuf;
#pragma unroll
        for (int i = 0; i < 8; ++i) {
            int q = i * 256 + tid;        // 0..2047
            dst[q] = src[q];
        }
        __syncthreads();

        const int kbase = c * CH_ + w * WCODES;
        const float* ew = ebuf + (w * WCODES) * D_;  // row-major [code][d]
#pragma unroll 2
        for (int kk = 0; kk < WCODES; ++kk) {
            const float* ek = ew + kk * D_;
            const float nk = ldsn[kbase + kk];       // uniform ds_read_b32, broadcast
            float acc0 = 0.f, acc1 = 0.f;
#pragma unroll
            for (int q = 0; q < 16; ++q) {
                float4 ev = *(const float4*)(ek + q * 4);  // uniform ds_read_b128
                acc0 = fmaf(x0[4 * q + 0], ev.x, acc0); acc1 = fmaf(x1[4 * q + 0], ev.x, acc1);
                acc0 = fmaf(x0[4 * q + 1], ev.y, acc0); acc1 = fmaf(x1[4 * q + 1], ev.y, acc1);
                acc0 = fmaf(x0[4 * q + 2], ev.z, acc0); acc1 = fmaf(x1[4 * q + 2], ev.z, acc1);
                acc0 = fmaf(x0[4 * q + 3], ev.w, acc0); acc1 = fmaf(x1[4 * q + 3], ev.w, acc1);
            }
            // dist = fp32(fp32(sx + n_k) - 2*dot); -2*acc exact, fadd==fma bitwise.
            // Strict < keeps first index within the wave's ascending scan.
            float t0 = __fadd_rn(sx0, nk);
            float v0 = __fadd_rn(t0, -2.0f * acc0);
            if (v0 < runv0) { runv0 = v0; runi0 = kbase + kk; }
            float t1 = __fadd_rn(sx1, nk);
            float v1 = __fadd_rn(t1, -2.0f * acc1);
            if (v1 < runv1) { runv1 = v1; runi1 = kbase + kk; }
        }
    }

    // ---- cross-wave argmin merge (code ranges interleave; idx tie-break handles) ----
    {
        const int p0 = 2 * lane, p1 = 2 * lane + 1;
        sv[w * M_ + p0] = runv0; si[w * M_ + p0] = runi0;
        sv[w * M_ + p1] = runv1; si[w * M_ + p1] = runi1;
    }
    __syncthreads();
    if (tid < M_) {
        float bv = 3.4e38f; int bi = 0x7fffffff;
#pragma unroll
        for (int g = 0; g < 4; ++g) {
            float v  = sv[g * M_ + tid];
            int   ii = si[g * M_ + tid];
            if (v < bv || (v == bv && ii < bi)) { bv = v; bi = ii; }
        }
        fi[tid] = bi;
        out[1 + NDTOT + n0 + tid] = (float)bi;   // idx as float
    }
    __syncthreads();

    // ---- loss: wave 0 only, from register-resident x (gathers are L2-hot) ----
    if (w == 0) {
        const int i0 = fi[2 * lane], i1 = fi[2 * lane + 1];
        const float* e0 = emb + i0 * D_;
        const float* e1 = emb + i1 * D_;
        float local = 0.f;
#pragma unroll
        for (int q = 0; q < 16; ++q) {
            float4 a0 = *(const float4*)(e0 + 4 * q);
            float4 a1 = *(const float4*)(e1 + 4 * q);
            float d00 = a0.x - x0[4 * q + 0]; local = fmaf(d00, d00, local);
            float d01 = a0.y - x0[4 * q + 1]; local = fmaf(d01, d01, local);
            float d02 = a0.z - x0[4 * q + 2]; local = fmaf(d02, d02, local);
            float d03 = a0.w - x0[4 * q + 3]; local = fmaf(d03, d03, local);
            float d10 = a1.x - x1[4 * q + 0]; local = fmaf(d10, d10, local);
            float d11 = a1.y - x1[4 * q + 1]; local = fmaf(d11, d11, local);
            float d12 = a1.z - x1[4 * q + 2]; local = fmaf(d12, d12, local);
            float d13 = a1.w - x1[4 * q + 3]; local = fmaf(d13, d13, local);
        }
#pragma unroll
        for (int off = 32; off > 0; off >>= 1)
            local += __shfl_down(local, off, 64);
        if (lane == 0)
            atomicAdd(out, local * (1.25f / (float)NDTOT));   // loss = 1.25 * mean((q-x)^2)
    }

    // ---- quantized output (NCHW): coalesced stores, per-lane emb row gathers ----
    float* obase = out + 1 + b * (D_ * HW_) + hw0;
    for (int i = 0; i < 32; ++i) {
        int q = i * 256 + tid;              // 0..8191 = 64 d * 128 p
        int d = q >> 7;
        int p = q & 127;
        obase[d * HW_ + p] = emb[fi[p] * D_ + d];
    }
}

extern "C" void kernel_launch(void* const* d_in, const int* in_sizes, int n_in,
                              void* d_out, int out_size, void* d_ws, size_t ws_size,
                              hipStream_t stream) {
    const float* inp = (const float*)d_in[0];
    const float* emb = (const float*)d_in[1];
    float* out = (float*)d_out;
    (void)d_ws; (void)ws_size;

    hipMemsetAsync(d_out, 0, sizeof(float), stream);   // loss accumulator
    vq_fused_kernel<<<512, 256, 0, stream>>>(inp, emb, out);
}

// Round 3
// 138.085 us; speedup vs baseline: 1.4694x; 1.1158x over previous
//
#include <hip/hip_runtime.h>

// VQ-VAE VectorQuantizer for MI355X — v4: x in VGPRs, e streamed through SGPRs (SMEM pipe).
// inputs: d_in[0] = inputs [64, 64, 32, 32] fp32 (NCHW), d_in[1] = emb_w [512, 64] fp32
// output d_out (fp32): [loss(1), quantized NCHW (64*64*32*32), idx (65536)]
//
// Correctness note: the reference computes dist = ||x||^2 + ||e||^2 - 2 x.e in fp32,
// where ||x||^2 ~ 64 quantizes dist to a ~7.6e-6 grid; ~100/65536 points have quantized
// TIES that argmin resolves by first index. We bit-replicate that arithmetic
// (numpy pairwise-sum order for the norms, fp32 rounding sequence for dist: sequential
// fmaf over d=0..63, then fp32((sx+nk) - 2*dot)) and tie-break by smallest index.
//
// v4 structure: v3 was LDS-pipe-THROUGHPUT-bound: 4.19M uniform ds_read_b128 total
// (16 per wave-code, fixed ratio) x ~12cy = ~82us of LDS pipe per CU vs 27us VALU floor
// (VALUBusy 42% = the ratio). Fix: e is wave-uniform -> stream it through the SCALAR
// pipe. Per code: 4x s_load_dwordx16 (inline asm, guaranteed SMEM; v2 showed the
// compiler demotes "uniform" C loads to per-lane VMEM) + s_waitcnt lgkmcnt(0) (SMEM
// returns out-of-order; counted waits unsafe) + 128 v_fma with SGPR e-operand.
// LDS pipe now carries only 1 uniform ds_read_b32 (nk) per code. No main-loop barriers.
// x: global->reg float2 (coalesced), pinned via empty asm "+v" so the compiler cannot
// re-sink the loads into the loop (v2 lesson: VGPR_Count=92 < 128 = re-sunk).
// SMEM latency per code is covered by the co-resident wave (2 blocks/CU).

typedef float f32x16 __attribute__((ext_vector_type(16)));

#define D_     64
#define HW_    1024
#define N_     65536
#define K_     512
#define M_     128    // points per block
#define WCODES 128    // codes per wave (4 waves split K)
#define NDTOT  (N_ * D_)

__global__ __launch_bounds__(256, 2) void vq_fused_kernel(const float* __restrict__ inp,
                                                          const float* __restrict__ emb,
                                                          float* __restrict__ out) {
    __shared__ float ldsn[K_];         // ||e_k||^2
    __shared__ float sv[4 * M_];       // per-wave argmin value
    __shared__ int   si[4 * M_];       // per-wave argmin index
    __shared__ int   fi[M_];           // final index per point

    const int tid  = threadIdx.x;
    const int lane = tid & 63;
    const int w    = tid >> 6;            // wave id 0..3 -> code range
    const int n0   = blockIdx.x * M_;
    const int b    = n0 >> 10;
    const int hw0  = n0 & 1023;

    // ---- x for points 2*lane, 2*lane+1: global -> regs (coalesced float2 per d) ----
    const float* xb = inp + b * (D_ * HW_) + hw0 + 2 * lane;
    float x0[64], x1[64];
#pragma unroll
    for (int d = 0; d < 64; ++d) {
        float2 v = *(const float2*)(xb + d * HW_);
        x0[d] = v.x; x1[d] = v.y;
    }
    // pin x into VGPRs: compiler must not re-sink these loads into the main loop
#pragma unroll
    for (int d = 0; d < 64; ++d) asm volatile("" : "+v"(x0[d]), "+v"(x1[d]));

    // ---- fused ||e_k||^2, numpy pairwise order (2 codes/thread), overlaps x loads ----
#pragma unroll
    for (int c = 0; c < 2; ++c) {
        const int k = c * 256 + tid;
        const float* e = emb + k * D_;
        float el[64];
#pragma unroll
        for (int q = 0; q < 16; ++q) {
            float4 v = *(const float4*)(e + q * 4);
            el[4 * q + 0] = v.x; el[4 * q + 1] = v.y;
            el[4 * q + 2] = v.z; el[4 * q + 3] = v.w;
        }
        float r[8];
#pragma unroll
        for (int j = 0; j < 8; ++j) r[j] = __fmul_rn(el[j], el[j]);
#pragma unroll
        for (int i = 1; i < 8; ++i)
#pragma unroll
            for (int j = 0; j < 8; ++j)
                r[j] = __fadd_rn(r[j], __fmul_rn(el[i * 8 + j], el[i * 8 + j]));
        ldsn[k] = __fadd_rn(__fadd_rn(__fadd_rn(r[0], r[1]), __fadd_rn(r[2], r[3])),
                            __fadd_rn(__fadd_rn(r[4], r[5]), __fadd_rn(r[6], r[7])));
    }

    // ---- ||x||^2, numpy pairwise order ----
    float r0[8], r1[8];
#pragma unroll
    for (int j = 0; j < 8; ++j) {
        r0[j] = __fmul_rn(x0[j], x0[j]);
        r1[j] = __fmul_rn(x1[j], x1[j]);
    }
#pragma unroll
    for (int i = 1; i < 8; ++i)
#pragma unroll
        for (int j = 0; j < 8; ++j) {
            r0[j] = __fadd_rn(r0[j], __fmul_rn(x0[i * 8 + j], x0[i * 8 + j]));
            r1[j] = __fadd_rn(r1[j], __fmul_rn(x1[i * 8 + j], x1[i * 8 + j]));
        }
    const float sx0 = __fadd_rn(__fadd_rn(__fadd_rn(r0[0], r0[1]), __fadd_rn(r0[2], r0[3])),
                                __fadd_rn(__fadd_rn(r0[4], r0[5]), __fadd_rn(r0[6], r0[7])));
    const float sx1 = __fadd_rn(__fadd_rn(__fadd_rn(r1[0], r1[1]), __fadd_rn(r1[2], r1[3])),
                                __fadd_rn(__fadd_rn(r1[4], r1[5]), __fadd_rn(r1[6], r1[7])));
    __syncthreads();   // ldsn ready

    // ---- main loop: wave w scans codes [w*128, w*128+128), e via s_load broadcast ----
    float runv0 = 3.4e38f, runv1 = 3.4e38f;
    int   runi0 = 0,       runi1 = 0;
    const int kb = __builtin_amdgcn_readfirstlane(w << 7);   // wave-uniform in SGPR
    const float* ew = emb + (size_t)kb * D_;

    for (int kk = 0; kk < WCODES; ++kk) {
        const float* ek = ew + kk * D_;                      // uniform chain -> SGPR pair
        f32x16 e0, e1, e2, e3;
        asm volatile(
            "s_load_dwordx16 %0, %4, 0x0\n\t"
            "s_load_dwordx16 %1, %4, 0x40\n\t"
            "s_load_dwordx16 %2, %4, 0x80\n\t"
            "s_load_dwordx16 %3, %4, 0xc0\n\t"
            "s_waitcnt lgkmcnt(0)"
            : "=s"(e0), "=s"(e1), "=s"(e2), "=s"(e3)
            : "s"(ek));
        const float nk = ldsn[kb + kk];                      // 1 uniform ds_read_b32
        float acc0 = 0.f, acc1 = 0.f;
        // exact sequential fmaf over d = 0..63 (order is bit-load-bearing)
#pragma unroll
        for (int j = 0; j < 16; ++j) {
            acc0 = fmaf(x0[j], e0[j], acc0);
            acc1 = fmaf(x1[j], e0[j], acc1);
        }
#pragma unroll
        for (int j = 0; j < 16; ++j) {
            acc0 = fmaf(x0[16 + j], e1[j], acc0);
            acc1 = fmaf(x1[16 + j], e1[j], acc1);
        }
#pragma unroll
        for (int j = 0; j < 16; ++j) {
            acc0 = fmaf(x0[32 + j], e2[j], acc0);
            acc1 = fmaf(x1[32 + j], e2[j], acc1);
        }
#pragma unroll
        for (int j = 0; j < 16; ++j) {
            acc0 = fmaf(x0[48 + j], e3[j], acc0);
            acc1 = fmaf(x1[48 + j], e3[j], acc1);
        }
        // dist = fp32(fp32(sx + n_k) - 2*dot); -2*acc exact, fadd==fma bitwise.
        // Strict < keeps first index within the wave's ascending scan.
        float t0 = __fadd_rn(sx0, nk);
        float v0 = __fadd_rn(t0, -2.0f * acc0);
        if (v0 < runv0) { runv0 = v0; runi0 = kb + kk; }
        float t1 = __fadd_rn(sx1, nk);
        float v1 = __fadd_rn(t1, -2.0f * acc1);
        if (v1 < runv1) { runv1 = v1; runi1 = kb + kk; }
    }

    // ---- cross-wave argmin merge (waves are ascending code blocks; idx tie-break) ----
    {
        const int p0 = 2 * lane, p1 = p0 + 1;
        sv[w * M_ + p0] = runv0; si[w * M_ + p0] = runi0;
        sv[w * M_ + p1] = runv1; si[w * M_ + p1] = runi1;
    }
    __syncthreads();
    if (tid < M_) {
        float bv = 3.4e38f; int bi = 0x7fffffff;
#pragma unroll
        for (int g = 0; g < 4; ++g) {
            float v  = sv[g * M_ + tid];
            int   ii = si[g * M_ + tid];
            if (v < bv || (v == bv && ii < bi)) { bv = v; bi = ii; }
        }
        fi[tid] = bi;
        out[1 + NDTOT + n0 + tid] = (float)bi;   // idx as float
    }
    __syncthreads();

    // ---- loss: wave 0 only, from register-resident x (row gathers, line-efficient) ----
    if (w == 0) {
        const int i0 = fi[2 * lane], i1 = fi[2 * lane + 1];
        const float* e0p = emb + i0 * D_;
        const float* e1p = emb + i1 * D_;
        float local = 0.f;
#pragma unroll
        for (int q = 0; q < 16; ++q) {
            float4 a0 = *(const float4*)(e0p + 4 * q);
            float4 a1 = *(const float4*)(e1p + 4 * q);
            float d00 = a0.x - x0[4 * q + 0]; local = fmaf(d00, d00, local);
            float d01 = a0.y - x0[4 * q + 1]; local = fmaf(d01, d01, local);
            float d02 = a0.z - x0[4 * q + 2]; local = fmaf(d02, d02, local);
            float d03 = a0.w - x0[4 * q + 3]; local = fmaf(d03, d03, local);
            float d10 = a1.x - x1[4 * q + 0]; local = fmaf(d10, d10, local);
            float d11 = a1.y - x1[4 * q + 1]; local = fmaf(d11, d11, local);
            float d12 = a1.z - x1[4 * q + 2]; local = fmaf(d12, d12, local);
            float d13 = a1.w - x1[4 * q + 3]; local = fmaf(d13, d13, local);
        }
#pragma unroll
        for (int off = 32; off > 0; off >>= 1)
            local += __shfl_down(local, off, 64);
        if (lane == 0)
            atomicAdd(out, local * (1.25f / (float)NDTOT));   // loss = 1.25*mean((q-x)^2)
    }

    // ---- quantized output: per-point ROW gather (line-efficient) + coalesced stores ----
    {
        const int p     = tid & 127;          // point
        const int dhalf = tid >> 7;           // 0/1 -> dims [32*dhalf, 32*dhalf+32)
        const float* er = emb + fi[p] * D_ + dhalf * 32;
        float ev[32];
#pragma unroll
        for (int q = 0; q < 8; ++q) {
            float4 v = *(const float4*)(er + 4 * q);
            ev[4 * q + 0] = v.x; ev[4 * q + 1] = v.y;
            ev[4 * q + 2] = v.z; ev[4 * q + 3] = v.w;
        }
        float* ob = out + 1 + b * (D_ * HW_) + hw0 + p;
#pragma unroll
        for (int dd = 0; dd < 32; ++dd)
            ob[(dhalf * 32 + dd) * HW_] = ev[dd];   // 128 consecutive floats per dd-group
    }
}

extern "C" void kernel_launch(void* const* d_in, const int* in_sizes, int n_in,
                              void* d_out, int out_size, void* d_ws, size_t ws_size,
                              hipStream_t stream) {
    const float* inp = (const float*)d_in[0];
    const float* emb = (const float*)d_in[1];
    float* out = (float*)d_out;
    (void)d_ws; (void)ws_size;

    hipMemsetAsync(d_out, 0, sizeof(float), stream);   // loss accumulator
    vq_fused_kernel<<<512, 256, 0, stream>>>(inp, emb, out);
}